// Round 1
// baseline (483.483 us; speedup 1.0000x reference)
//
#include <hip/hip_runtime.h>

typedef __attribute__((ext_vector_type(8))) short bf16x8;
typedef __attribute__((ext_vector_type(4))) float f32x4;

#define SDIM 2048
#define DDIM 64
#define NBH  32

__device__ __forceinline__ unsigned short f2bf(float f) {
    union { float f; unsigned int u; } x;
    x.f = f;
    unsigned int u = x.u;
    u += 0x7FFFu + ((u >> 16) & 1u);  // round-to-nearest-even
    return (unsigned short)(u >> 16);
}

__device__ __forceinline__ unsigned int packbf(float a, float b) {
    return (unsigned int)f2bf(a) | ((unsigned int)f2bf(b) << 16);
}

// transpose [bh][R][C] f32 -> [bh][C][R] bf16(ushort), 64x64 tiles via LDS
__global__ __launch_bounds__(256) void transpose_cvt(
    const float* __restrict__ in, unsigned short* __restrict__ out,
    int R, int C)
{
    __shared__ float tile[64][65];
    const int bh = blockIdx.z;
    const int ct = blockIdx.x * 64;
    const int rt = blockIdx.y * 64;
    const float* src = in + (size_t)bh * R * C;
    unsigned short* dst = out + (size_t)bh * R * C;
    const int r = threadIdx.x >> 2;   // 0..63
    const int p = threadIdx.x & 3;    // 0..3
    const float* sp = src + (size_t)(rt + r) * C + ct + p * 16;
#pragma unroll
    for (int j = 0; j < 4; ++j) {
        float4 a = *(const float4*)(sp + j * 4);
        tile[r][p*16 + j*4 + 0] = a.x;
        tile[r][p*16 + j*4 + 1] = a.y;
        tile[r][p*16 + j*4 + 2] = a.z;
        tile[r][p*16 + j*4 + 3] = a.w;
    }
    __syncthreads();
    uint4 w0, w1;
    w0.x = packbf(tile[p*16+ 0][r], tile[p*16+ 1][r]);
    w0.y = packbf(tile[p*16+ 2][r], tile[p*16+ 3][r]);
    w0.z = packbf(tile[p*16+ 4][r], tile[p*16+ 5][r]);
    w0.w = packbf(tile[p*16+ 6][r], tile[p*16+ 7][r]);
    w1.x = packbf(tile[p*16+ 8][r], tile[p*16+ 9][r]);
    w1.y = packbf(tile[p*16+10][r], tile[p*16+11][r]);
    w1.z = packbf(tile[p*16+12][r], tile[p*16+13][r]);
    w1.w = packbf(tile[p*16+14][r], tile[p*16+15][r]);
    unsigned short* dp = dst + (size_t)(ct + r) * R + rt + p * 16;
    *(uint4*)dp = w0;
    *(uint4*)(dp + 8) = w1;
}

// Fused: scores = q@k*scale + prev (written out), softmax, @v (written out).
// Block: 256 threads = 4 waves; each wave owns 16 Q rows; Q-tile = 64 rows.
__global__ __launch_bounds__(256) void attn_fused(
    const float* __restrict__ q, const float* __restrict__ prev,
    const unsigned short* __restrict__ kT, const unsigned short* __restrict__ vT,
    float* __restrict__ out, float* __restrict__ scores)
{
    const int bh   = blockIdx.y;
    const int qt   = blockIdx.x;          // 64-row Q tile index
    const int tid  = threadIdx.x;
    const int wave = tid >> 6;
    const int lane = tid & 63;
    const int ln   = lane & 15;           // 0..15
    const int lg   = lane >> 4;           // 0..3

    __shared__ unsigned short p_lds[4][16][72];   // per-wave P tile, padded

    // ---- Q fragments (A operand: row = ln, k(d) = kc*32 + lg*8 + j) ----
    const int qrow_frag = qt * 64 + wave * 16 + ln;
    bf16x8 qf[2];
    {
        const float* qp = q + ((size_t)bh * SDIM + qrow_frag) * DDIM + lg * 8;
#pragma unroll
        for (int kc = 0; kc < 2; ++kc) {
            float4 a = *(const float4*)(qp + kc * 32);
            float4 b = *(const float4*)(qp + kc * 32 + 4);
            bf16x8 f;
            f[0] = (short)f2bf(a.x); f[1] = (short)f2bf(a.y);
            f[2] = (short)f2bf(a.z); f[3] = (short)f2bf(a.w);
            f[4] = (short)f2bf(b.x); f[5] = (short)f2bf(b.y);
            f[6] = (short)f2bf(b.z); f[7] = (short)f2bf(b.w);
            qf[kc] = f;
        }
    }

    // C/D rows for this lane: qrow_c + r, r = 0..3
    const int qrow_c = qt * 64 + wave * 16 + lg * 4;

    f32x4 oacc[4] = {};
    float m[4], l[4];
#pragma unroll
    for (int r = 0; r < 4; ++r) { m[r] = -1e30f; l[r] = 0.0f; }

    const size_t prev_base = ((size_t)bh * SDIM + qrow_c) * SDIM;
    const unsigned short* kbase = kT + ((size_t)bh * SDIM + ln) * DDIM + lg * 8;
    const unsigned short* vbase = vT + ((size_t)bh * DDIM + ln) * SDIM + lg * 8;

    for (int t0 = 0; t0 < SDIM; t0 += 64) {
        // ---- S = Q @ K^T over this 64-col tile ----
        f32x4 sacc[4] = {};
#pragma unroll
        for (int nc = 0; nc < 4; ++nc) {
#pragma unroll
            for (int kc = 0; kc < 2; ++kc) {
                bf16x8 bf = *(const bf16x8*)(kbase + (size_t)(t0 + nc * 16) * DDIM + kc * 32);
                sacc[nc] = __builtin_amdgcn_mfma_f32_16x16x32_bf16(qf[kc], bf, sacc[nc], 0, 0, 0);
            }
        }

        // ---- scale + prev, write scores, keep in regs ----
        float sv[4][4];
#pragma unroll
        for (int nc = 0; nc < 4; ++nc) {
#pragma unroll
            for (int r = 0; r < 4; ++r) {
                size_t idx = prev_base + (size_t)r * SDIM + (t0 + nc * 16 + ln);
                float s = sacc[nc][r] * 0.125f + __builtin_nontemporal_load(&prev[idx]);
                __builtin_nontemporal_store(s, &scores[idx]);
                sv[nc][r] = s;
            }
        }

        // ---- online softmax (rows replicated across the 16-lane group) ----
        float corr[4];
#pragma unroll
        for (int r = 0; r < 4; ++r) {
            float mx = fmaxf(fmaxf(sv[0][r], sv[1][r]), fmaxf(sv[2][r], sv[3][r]));
#pragma unroll
            for (int off = 1; off < 16; off <<= 1)
                mx = fmaxf(mx, __shfl_xor(mx, off, 64));
            float mn = fmaxf(m[r], mx);
            corr[r] = __expf(m[r] - mn);
            float psum = 0.0f;
#pragma unroll
            for (int nc = 0; nc < 4; ++nc) {
                float pv = __expf(sv[nc][r] - mn);
                sv[nc][r] = pv;
                psum += pv;
            }
#pragma unroll
            for (int off = 1; off < 16; off <<= 1)
                psum += __shfl_xor(psum, off, 64);
            l[r] = l[r] * corr[r] + psum;
            m[r] = mn;
        }
#pragma unroll
        for (int nc = 0; nc < 4; ++nc)
#pragma unroll
            for (int r = 0; r < 4; ++r)
                oacc[nc][r] *= corr[r];

        // ---- P -> bf16 -> LDS (C-layout write), read back as A-fragments ----
#pragma unroll
        for (int nc = 0; nc < 4; ++nc)
#pragma unroll
            for (int r = 0; r < 4; ++r)
                p_lds[wave][lg * 4 + r][nc * 16 + ln] = f2bf(sv[nc][r]);

        bf16x8 pa[2];
#pragma unroll
        for (int kc = 0; kc < 2; ++kc)
            pa[kc] = *(const bf16x8*)&p_lds[wave][ln][kc * 32 + lg * 8];

        // ---- O += P @ V ----
#pragma unroll
        for (int nc = 0; nc < 4; ++nc) {
#pragma unroll
            for (int kc = 0; kc < 2; ++kc) {
                bf16x8 vf = *(const bf16x8*)(vbase + (size_t)nc * 16 * SDIM + (t0 + kc * 32));
                oacc[nc] = __builtin_amdgcn_mfma_f32_16x16x32_bf16(pa[kc], vf, oacc[nc], 0, 0, 0);
            }
        }
    }

    // ---- epilogue: normalize and write output ----
#pragma unroll
    for (int nc = 0; nc < 4; ++nc) {
#pragma unroll
        for (int r = 0; r < 4; ++r) {
            size_t oidx = ((size_t)bh * SDIM + qrow_c + r) * DDIM + nc * 16 + ln;
            out[oidx] = oacc[nc][r] / l[r];
        }
    }
}

extern "C" void kernel_launch(void* const* d_in, const int* in_sizes, int n_in,
                              void* d_out, int out_size, void* d_ws, size_t ws_size,
                              hipStream_t stream) {
    const float* q    = (const float*)d_in[0];
    const float* k    = (const float*)d_in[1];
    const float* v    = (const float*)d_in[2];
    const float* prev = (const float*)d_in[3];

    float* out    = (float*)d_out;
    float* scores = out + (size_t)NBH * SDIM * DDIM;   // outputs concatenated

    unsigned short* kT = (unsigned short*)d_ws;                 // [bh][2048][64] bf16
    unsigned short* vT = kT + (size_t)NBH * SDIM * DDIM;        // [bh][64][2048] bf16

    // k: [bh][64][2048] -> kT [bh][2048][64]
    transpose_cvt<<<dim3(SDIM / 64, 1, NBH), 256, 0, stream>>>(k, kT, DDIM, SDIM);
    // v: [bh][2048][64] -> vT [bh][64][2048]
    transpose_cvt<<<dim3(1, SDIM / 64, NBH), 256, 0, stream>>>(v, vT, SDIM, DDIM);

    attn_fused<<<dim3(SDIM / 64, NBH), 256, 0, stream>>>(q, prev, kT, vT, out, scores);
}